// Round 1
// baseline (763.718 us; speedup 1.0000x reference)
//
#include <hip/hip_runtime.h>
#include <hip/hip_bf16.h>

// CxNNxNN attention. B=8, C=64, H=W=256, head=8, N=8.
// token n = (h&7)*8 + (w&7)  [64], feature d = (h>>3)*32 + (w>>3)  [1024].

#define LSTR 68  // LDS row stride (floats); 68 => <=2-way bank aliasing for our patterns

// ---------------- K1: pointwise qkv = w_qkv @ x ----------------
__global__ __launch_bounds__(256) void k_pointwise(
    const float* __restrict__ x, const float* __restrict__ wqkv,
    float* __restrict__ qkv0) {
  int pix = blockIdx.x * 256 + threadIdx.x;
  int b = pix >> 16, hw = pix & 65535;
  const float* xb = x + ((size_t)b << 22) + hw;  // b*64*65536
  float xr[64];
#pragma unroll
  for (int c = 0; c < 64; ++c) xr[c] = xb[(size_t)c << 16];
  float* ob = qkv0 + (((size_t)b * 192) << 16) + hw;
#pragma unroll 1
  for (int oc = 0; oc < 192; oc += 16) {
    float acc[16];
#pragma unroll
    for (int j = 0; j < 16; ++j) acc[j] = 0.f;
#pragma unroll 4
    for (int c = 0; c < 64; ++c) {
      float xv = xr[c];
#pragma unroll
      for (int j = 0; j < 16; ++j)
        acc[j] = fmaf(wqkv[(oc + j) * 64 + c], xv, acc[j]);  // uniform -> s_load
    }
#pragma unroll
    for (int j = 0; j < 16; ++j) ob[(size_t)(oc + j) << 16] = acc[j];
  }
}

// ---- fused depthwise-3x3 conv + permuted staging into LDS [64 n][64 dcol] ----
// chunk cd covers d in [cd*64, cd*64+64)  <=> image rows h in [cd*16, cd*16+16)
__device__ __forceinline__ void stage_conv(const float* __restrict__ pl,
                                           const float* __restrict__ w9,
                                           float* __restrict__ lds, int cd,
                                           int t) {
#pragma unroll
  for (int rr = 0; rr < 2; ++rr) {
    int r = t + rr * 256;          // 512 runs: 16 rows x 32 w-tiles
    int lr = r >> 5, w0 = r & 31;  // local row, w-tile (8 px)
    int h = cd * 16 + lr;
    float rv[3][10];
#pragma unroll
    for (int dy = 0; dy < 3; ++dy) {
      int hy = h + dy - 1;
      bool hv = (hy >= 0) && (hy < 256);
#pragma unroll
      for (int j = 0; j < 10; ++j) rv[dy][j] = 0.f;
      if (hv) {
        const float* rp = pl + hy * 256;
        const float4* rp4 = (const float4*)(rp + w0 * 8);
        float4 a = rp4[0], b4 = rp4[1];
        rv[dy][1] = a.x;  rv[dy][2] = a.y;  rv[dy][3] = a.z;  rv[dy][4] = a.w;
        rv[dy][5] = b4.x; rv[dy][6] = b4.y; rv[dy][7] = b4.z; rv[dy][8] = b4.w;
        rv[dy][0] = (w0 > 0) ? rp[w0 * 8 - 1] : 0.f;   // left halo / zero pad
        rv[dy][9] = (w0 < 31) ? rp[w0 * 8 + 8] : 0.f;  // right halo / zero pad
      }
    }
    int nb = (lr & 7) * 8;               // n base (nh*8), i -> nw
    int dcol = ((lr >> 3) << 5) + w0;    // local d column
#pragma unroll
    for (int i = 0; i < 8; ++i) {
      float o = fmaf(w9[0], rv[0][i], fmaf(w9[1], rv[0][i + 1], fmaf(w9[2], rv[0][i + 2],
                fmaf(w9[3], rv[1][i], fmaf(w9[4], rv[1][i + 1], fmaf(w9[5], rv[1][i + 2],
                fmaf(w9[6], rv[2][i], fmaf(w9[7], rv[2][i + 1], w9[8] * rv[2][i + 2]))))))));
      lds[(nb + i) * LSTR + dcol] = o;
    }
  }
}

// ---------------- K2: per-(b,ch) attention, conv fused in staging -------------
__global__ __launch_bounds__(256) void k_attn(
    const float* __restrict__ qkv0, const float* __restrict__ wdw,
    const float* __restrict__ temperature, float* __restrict__ out) {
  __shared__ float bufA[64 * LSTR];  // Q chunks, then P^T
  __shared__ float bufB[64 * LSTR];  // K chunks, then V chunks
  __shared__ float red[64 * 8];
  __shared__ float invn[128];

  const int t = threadIdx.x;
  const int b = blockIdx.x >> 6, ch = blockIdx.x & 63;
  const float* qpl = qkv0 + (((size_t)b * 192 + ch) << 16);
  const float* kpl = qkv0 + (((size_t)b * 192 + 64 + ch) << 16);
  const float* vpl = qkv0 + (((size_t)b * 192 + 128 + ch) << 16);
  float wq[9], wk[9], wv[9];
#pragma unroll
  for (int i = 0; i < 9; ++i) {  // uniform indices -> scalar regs
    wq[i] = wdw[ch * 9 + i];
    wk[i] = wdw[(64 + ch) * 9 + i];
    wv[i] = wdw[(128 + ch) * 9 + i];
  }
  const float tscale = temperature[ch >> 3];

  const int tn = t >> 4, tmw = t & 15;  // S tile: rows tn*4+i, cols tmw+16*j
  float s_acc[4][4];
#pragma unroll
  for (int i = 0; i < 4; ++i)
#pragma unroll
    for (int j = 0; j < 4; ++j) s_acc[i][j] = 0.f;
  float sqQ = 0.f, sqK = 0.f;

  for (int cd = 0; cd < 16; ++cd) {
    stage_conv(qpl, wq, bufA, cd, t);
    stage_conv(kpl, wk, bufB, cd, t);
    __syncthreads();
    {  // sumsq partials: row n = t>>2, 16 cols
      int n = t >> 2, d0 = (t & 3) << 4;
#pragma unroll
      for (int k4 = 0; k4 < 4; ++k4) {
        float4 qv = *(const float4*)&bufA[n * LSTR + d0 + k4 * 4];
        float4 kv = *(const float4*)&bufB[n * LSTR + d0 + k4 * 4];
        sqQ += qv.x * qv.x + qv.y * qv.y + qv.z * qv.z + qv.w * qv.w;
        sqK += kv.x * kv.x + kv.y * kv.y + kv.z * kv.z + kv.w * kv.w;
      }
    }
#pragma unroll 2
    for (int ds = 0; ds < 16; ++ds) {
      float qv[4][4], kv[4][4];
#pragma unroll
      for (int i = 0; i < 4; ++i) {
        float4 v4 = *(const float4*)&bufA[(tn * 4 + i) * LSTR + ds * 4];
        qv[i][0] = v4.x; qv[i][1] = v4.y; qv[i][2] = v4.z; qv[i][3] = v4.w;
      }
#pragma unroll
      for (int j = 0; j < 4; ++j) {
        float4 v4 = *(const float4*)&bufB[(tmw + 16 * j) * LSTR + ds * 4];
        kv[j][0] = v4.x; kv[j][1] = v4.y; kv[j][2] = v4.z; kv[j][3] = v4.w;
      }
#pragma unroll
      for (int i = 0; i < 4; ++i)
#pragma unroll
        for (int j = 0; j < 4; ++j) {
          float s = s_acc[i][j];
          s = fmaf(qv[i][0], kv[j][0], s);
          s = fmaf(qv[i][1], kv[j][1], s);
          s = fmaf(qv[i][2], kv[j][2], s);
          s = fmaf(qv[i][3], kv[j][3], s);
          s_acc[i][j] = s;
        }
    }
    __syncthreads();
  }

  // reduce sumsq -> 1/max(||.||, 1e-12)
  red[(t >> 2) * 8 + (t & 3)] = sqQ;
  red[(t >> 2) * 8 + 4 + (t & 3)] = sqK;
  __syncthreads();
  if (t < 128) {
    int n = t & 63;
    int o = (t >> 6) * 4;
    float s = red[n * 8 + o] + red[n * 8 + o + 1] + red[n * 8 + o + 2] +
              red[n * 8 + o + 3];
    invn[(t >> 6) * 64 + n] = 1.f / fmaxf(sqrtf(s), 1e-12f);
  }
  __syncthreads();

  // scale + softmax over m (16-lane shfl groups)
  float iq[4], ik[4];
#pragma unroll
  for (int i = 0; i < 4; ++i) iq[i] = invn[tn * 4 + i];
#pragma unroll
  for (int j = 0; j < 4; ++j) ik[j] = invn[64 + tmw + 16 * j];
#pragma unroll
  for (int i = 0; i < 4; ++i) {
#pragma unroll
    for (int j = 0; j < 4; ++j) s_acc[i][j] *= iq[i] * ik[j] * tscale;
    float m = fmaxf(fmaxf(s_acc[i][0], s_acc[i][1]),
                    fmaxf(s_acc[i][2], s_acc[i][3]));
#pragma unroll
    for (int off = 1; off < 16; off <<= 1) m = fmaxf(m, __shfl_xor(m, off));
    float ssum = 0.f;
#pragma unroll
    for (int j = 0; j < 4; ++j) {
      s_acc[i][j] = __expf(s_acc[i][j] - m);
      ssum += s_acc[i][j];
    }
#pragma unroll
    for (int off = 1; off < 16; off <<= 1) ssum += __shfl_xor(ssum, off);
    float rs = 1.f / ssum;
#pragma unroll
    for (int j = 0; j < 4; ++j) s_acc[i][j] *= rs;
  }

  // write P^T into bufA (phase-1 reads of bufA all completed before red barrier)
#pragma unroll
  for (int j = 0; j < 4; ++j) {
    float4 c4 = make_float4(s_acc[0][j], s_acc[1][j], s_acc[2][j], s_acc[3][j]);
    *(float4*)&bufA[(tmw + 16 * j) * LSTR + tn * 4] = c4;
  }
  __syncthreads();

  // phase 3: O = P V, stream conv'd V chunks; write raster into out
  const int td = tmw;
  size_t obase = ((size_t)b * 64 + ch) << 16;
  for (int cd = 0; cd < 16; ++cd) {
    stage_conv(vpl, wv, bufB, cd, t);
    __syncthreads();
    float oa[4][4];
#pragma unroll
    for (int i = 0; i < 4; ++i)
#pragma unroll
      for (int j = 0; j < 4; ++j) oa[i][j] = 0.f;
#pragma unroll 2
    for (int m = 0; m < 64; ++m) {
      float4 p4 = *(const float4*)&bufA[m * LSTR + tn * 4];
      float4 v4 = *(const float4*)&bufB[m * LSTR + td * 4];
      float pv[4] = {p4.x, p4.y, p4.z, p4.w};
      float vv[4] = {v4.x, v4.y, v4.z, v4.w};
#pragma unroll
      for (int i = 0; i < 4; ++i)
#pragma unroll
        for (int j = 0; j < 4; ++j) oa[i][j] = fmaf(pv[i], vv[j], oa[i][j]);
    }
#pragma unroll
    for (int i = 0; i < 4; ++i) {
      int n = tn * 4 + i;
      int hb = n >> 3, wb = n & 7;
#pragma unroll
      for (int j = 0; j < 4; ++j) {
        int d = cd * 64 + td * 4 + j;
        int h = ((d >> 5) << 3) + hb;
        int w = ((d & 31) << 3) + wb;
        out[obase + h * 256 + w] = oa[i][j];
      }
    }
    __syncthreads();
  }
}

// ---------------- K3: in-place 1x1 proj on d_out ----------------
__global__ __launch_bounds__(256) void k_proj(float* __restrict__ io,
                                              const float* __restrict__ wp) {
  int pix = blockIdx.x * 256 + threadIdx.x;
  int b = pix >> 16, hw = pix & 65535;
  float* base = io + ((size_t)b << 22) + hw;
  float a[64];
#pragma unroll
  for (int c = 0; c < 64; ++c) a[c] = base[(size_t)c << 16];  // all loads first
#pragma unroll 1
  for (int oc = 0; oc < 64; oc += 16) {
    float acc[16];
#pragma unroll
    for (int j = 0; j < 16; ++j) acc[j] = 0.f;
#pragma unroll 4
    for (int c = 0; c < 64; ++c) {
      float av = a[c];
#pragma unroll
      for (int j = 0; j < 16; ++j)
        acc[j] = fmaf(wp[(oc + j) * 64 + c], av, acc[j]);
    }
#pragma unroll
    for (int j = 0; j < 16; ++j) base[(size_t)(oc + j) << 16] = acc[j];
  }
}

extern "C" void kernel_launch(void* const* d_in, const int* in_sizes, int n_in,
                              void* d_out, int out_size, void* d_ws,
                              size_t ws_size, hipStream_t stream) {
  const float* x = (const float*)d_in[0];
  const float* wqkv = (const float*)d_in[1];
  const float* wdw = (const float*)d_in[2];
  const float* wproj = (const float*)d_in[3];
  const float* temp = (const float*)d_in[4];
  float* out = (float*)d_out;
  float* qkv0 = (float*)d_ws;  // 8*192*65536*4 = 402,653,184 bytes

  k_pointwise<<<2048, 256, 0, stream>>>(x, wqkv, qkv0);
  k_attn<<<512, 256, 0, stream>>>(qkv0, wdw, temp, out);
  k_proj<<<2048, 256, 0, stream>>>(out, wproj);
}